// Round 1
// baseline (315.501 us; speedup 1.0000x reference)
//
#include <hip/hip_runtime.h>
#include <math.h>

#define T_STEPS 256
#define BATCH   2048
#define HID     10

// fast activations (v_exp_f32 / v_log_f32 / v_rcp_f32 paths)
__device__ __forceinline__ float ftanh(float x){ return 1.f - 2.f/(1.f + __expf(2.f*x)); }
__device__ __forceinline__ float fsigm(float x){ return 1.f/(1.f + __expf(-x)); }
__device__ __forceinline__ float frcp (float x){ return __builtin_amdgcn_rcpf(x); }

// broadcast lane (group_base + I) to all 16 lanes of the group (static ds_swizzle)
template<int I> __device__ __forceinline__ float bc16(float x){
  return __int_as_float(__builtin_amdgcn_ds_swizzle(__float_as_int(x), (I<<5)|0x10));
}
// xor-butterfly within 16-lane group
template<int X> __device__ __forceinline__ float xor16(float x){
  return __int_as_float(__builtin_amdgcn_ds_swizzle(__float_as_int(x), (X<<10)|0x1f));
}
__device__ __forceinline__ float redsum16(float v){
  v += xor16<1>(v); v += xor16<2>(v); v += xor16<4>(v); v += xor16<8>(v);
  return v;
}

#define GATHER10(dst, src) do { \
  dst[0]=bc16<0>(src); dst[1]=bc16<1>(src); dst[2]=bc16<2>(src); \
  dst[3]=bc16<3>(src); dst[4]=bc16<4>(src); dst[5]=bc16<5>(src); \
  dst[6]=bc16<6>(src); dst[7]=bc16<7>(src); dst[8]=bc16<8>(src); \
  dst[9]=bc16<9>(src); } while(0)

__device__ __forceinline__ float mv10(const float* in, const float* w, float bias){
  float a = bias;
  #pragma unroll
  for (int i=0;i<HID;i++) a = fmaf(in[i], w[i], a);
  return a;
}

struct P34 { const float* p[34]; float* out; };

// one chain per 16 lanes: lane j owns hidden unit j (j<10), lanes 10..15 idle-but-uniform
__global__ __launch_bounds__(256) void dvbf_fwd(P34 prm)
{
  const int tid = threadIdx.x;
  const int j   = tid & 15;
  const int grp = tid >> 4;                 // 0..15 in block
  const int b   = blockIdx.x * 16 + grp;    // chain id
  const bool act = (j < HID);
  const int  jl  = act ? j : (HID-1);       // clamped index (no OOB loads)

  const float* __restrict__ seq   = prm.p[0];
  const float* __restrict__ noise = prm.p[1];
  float* __restrict__ out = prm.out;

  // ---------- per-lane weight columns (compile-time indexed -> VGPRs) ----------
  float w_fi_in[2], w_fi_h[10], w_fi_mu[10], w_fi_sg[10];
  float b_fi_in, b_fi_h, b_fi_mu, b_fi_sg;
  float w_in_in[2], w_in_j[20], w_in_h[10], w_in_mu[10], w_in_sg[10];
  float b_in_in, b_in_j, b_in_h, b_in_mu, b_in_sg;
  float w_tr_h[10], w_tr_mu[10], w_tr_sg[10];
  float b_tr_h, b_tr_mu, b_tr_sg;
  float w_g1[10], w_g2[10], w_go[10];
  float b_g1, b_g2, b_go;
  {
    const float* W;
    W = prm.p[2];
    #pragma unroll
    for (int i=0;i<2;i++)  w_fi_in[i] = act ? W[i*10+jl] : 0.f;
    b_fi_in = act ? prm.p[3][jl] : 0.f;
    W = prm.p[4];
    #pragma unroll
    for (int i=0;i<10;i++) w_fi_h[i]  = act ? W[i*10+jl] : 0.f;
    b_fi_h  = act ? prm.p[5][jl] : 0.f;
    W = prm.p[6];
    #pragma unroll
    for (int i=0;i<10;i++) w_fi_mu[i] = act ? W[i*10+jl] : 0.f;
    b_fi_mu = act ? prm.p[7][jl] : 0.f;
    W = prm.p[8];
    #pragma unroll
    for (int i=0;i<10;i++) w_fi_sg[i] = act ? W[i*10+jl] : 0.f;
    b_fi_sg = act ? prm.p[9][jl] : 0.f;

    W = prm.p[10];
    #pragma unroll
    for (int i=0;i<2;i++)  w_in_in[i] = act ? W[i*10+jl] : 0.f;
    b_in_in = act ? prm.p[11][jl] : 0.f;
    W = prm.p[12];
    #pragma unroll
    for (int i=0;i<20;i++) w_in_j[i]  = act ? W[i*10+jl] : 0.f;
    b_in_j  = act ? prm.p[13][jl] : 0.f;
    W = prm.p[14];
    #pragma unroll
    for (int i=0;i<10;i++) w_in_h[i]  = act ? W[i*10+jl] : 0.f;
    b_in_h  = act ? prm.p[15][jl] : 0.f;
    W = prm.p[16];
    #pragma unroll
    for (int i=0;i<10;i++) w_in_mu[i] = act ? W[i*10+jl] : 0.f;
    b_in_mu = act ? prm.p[17][jl] : 0.f;
    W = prm.p[18];
    #pragma unroll
    for (int i=0;i<10;i++) w_in_sg[i] = act ? W[i*10+jl] : 0.f;
    b_in_sg = act ? prm.p[19][jl] : 0.f;

    W = prm.p[20];
    #pragma unroll
    for (int i=0;i<10;i++) w_tr_h[i]  = act ? W[i*10+jl] : 0.f;
    b_tr_h  = act ? prm.p[21][jl] : 0.f;
    W = prm.p[22];
    #pragma unroll
    for (int i=0;i<10;i++) w_tr_mu[i] = act ? W[i*10+jl] : 0.f;
    b_tr_mu = act ? prm.p[23][jl] : 0.f;
    W = prm.p[24];
    #pragma unroll
    for (int i=0;i<10;i++) w_tr_sg[i] = act ? W[i*10+jl] : 0.f;
    b_tr_sg = act ? prm.p[25][jl] : 0.f;

    W = prm.p[26];
    #pragma unroll
    for (int i=0;i<10;i++) w_g1[i] = act ? W[i*10+jl] : 0.f;
    b_g1 = act ? prm.p[27][jl] : 0.f;
    W = prm.p[28];
    #pragma unroll
    for (int i=0;i<10;i++) w_g2[i] = act ? W[i*10+jl] : 0.f;
    b_g2 = act ? prm.p[29][jl] : 0.f;

    // packed generator output: lane0=mu col0, lane1=mu col1, lane2=sg col0, lane3=sg col1
    const float* Wgo = (j<2) ? prm.p[30] : prm.p[32];
    const float* Bgo = (j<2) ? prm.p[31] : prm.p[33];
    const int d = j & 1;
    #pragma unroll
    for (int i=0;i<10;i++) w_go[i] = (j<4) ? Wgo[i*2+d] : 0.f;
    b_go = (j<4) ? Bgo[d] : 0.f;
  }

  const float LOGPI = 1.1447298858494002f;

  float zv[10];   // gathered latent state (replicated across the 16 lanes)
  float loss;

  int sOff = b*2;           // sequence [t][b][:]
  int nOff = b*10 + jl;     // noise   [t][b][j]
  int gOff = b*2;           // generations [t][b][:]

  // generator: zv -> (m0,m1,ll) ; also stores handled by caller
  auto generator = [&](const float* zvv, float x0, float x1,
                       float& m0, float& m1, float& ll){
    float g1 = fmaxf(mv10(zvv, w_g1, b_g1), 0.f);
    float g1v[10]; GATHER10(g1v, g1);
    float g2 = fmaxf(mv10(g1v, w_g2, b_g2), 0.f);
    float g2v[10]; GATHER10(g2v, g2);
    float go = fsigm(mv10(g2v, w_go, b_go));
    m0 = bc16<0>(go); m1 = bc16<1>(go);
    float s0 = bc16<2>(go), s1 = bc16<3>(go);
    float d0 = x0 - m0, d1 = x1 - m1;
    ll = -0.5f*(__logf(s0) + __logf(s1) + d0*d0*frcp(s0) + d1*d1*frcp(s1) + 2.f*LOGPI);
  };

  // ---------- t = 0: first_inference vs unit prior ----------
  {
    float2 x = *reinterpret_cast<const float2*>(seq + sOff);
    float eps = noise[nOff];
    float h0 = ftanh(fmaf(x.x, w_fi_in[0], fmaf(x.y, w_fi_in[1], b_fi_in)));
    float hv[10]; GATHER10(hv, h0);
    float h1 = ftanh(mv10(hv, w_fi_h, b_fi_h));
    GATHER10(hv, h1);
    float mu = ftanh(mv10(hv, w_fi_mu, b_fi_mu));
    float sg = fsigm(mv10(hv, w_fi_sg, b_fi_sg)) + 0.001f;
    float term = act ? (sg + mu*mu - __logf(sg)) : 0.f;
    float kl = 0.5f*(redsum16(term) - (float)HID);
    float zj = fmaf(sg, eps, mu);
    GATHER10(zv, zj);
    float m0, m1, ll;
    generator(zv, x.x, x.y, m0, m1, ll);
    if (j < 2) out[gOff + j] = (j==0) ? m0 : m1;
    loss = kl + ll;
  }

  // ---------- t = 1 .. 255 ----------
  for (int t = 1; t < T_STEPS; ++t){
    sOff += BATCH*2; nOff += BATCH*10; gOff += BATCH*2;
    float2 x = *reinterpret_cast<const float2*>(seq + sOff);
    float eps = noise[nOff];

    // transition (prior)
    float th = ftanh(mv10(zv, w_tr_h, b_tr_h));
    float thv[10]; GATHER10(thv, th);
    float pr_mu = ftanh(mv10(thv, w_tr_mu, b_tr_mu));
    float pr_sg = ftanh(mv10(thv, w_tr_sg, b_tr_sg));

    // inference (posterior)
    float e = ftanh(fmaf(x.x, w_in_in[0], fmaf(x.y, w_in_in[1], b_in_in)));
    float ev[10]; GATHER10(ev, e);
    float a = b_in_j;
    #pragma unroll
    for (int i=0;i<10;i++) a = fmaf(ev[i], w_in_j[i], a);
    #pragma unroll
    for (int i=0;i<10;i++) a = fmaf(zv[i], w_in_j[10+i], a);
    float hj = ftanh(a);
    float hjv[10]; GATHER10(hjv, hj);
    float hi = ftanh(mv10(hjv, w_in_h, b_in_h));
    float hiv[10]; GATHER10(hiv, hi);
    float q_mu = ftanh(mv10(hiv, w_in_mu, b_in_mu));
    float q_sg = fsigm(mv10(hiv, w_in_sg, b_in_sg)) + 0.001f;

    // KLD (elementwise term per lane, then 16-lane butterfly; inactive lanes masked to 0)
    float dmu = pr_mu - q_mu;
    float rp  = frcp(pr_sg);
    float term = act ? (__logf(pr_sg) - __logf(q_sg) + q_sg*rp + dmu*dmu*rp) : 0.f;
    float kl = 0.5f*(redsum16(term) - (float)HID);

    // reparameterized sample
    float zj = fmaf(q_sg, eps, q_mu);
    GATHER10(zv, zj);

    // generator + GLL
    float m0, m1, ll;
    generator(zv, x.x, x.y, m0, m1, ll);
    if (j < 2) out[gOff + j] = (j==0) ? m0 : m1;
    loss += kl + ll;
  }

  if (j == 0) out[T_STEPS*BATCH*2 + b] = -loss * (1.0f/(float)T_STEPS);
}

extern "C" void kernel_launch(void* const* d_in, const int* in_sizes, int n_in,
                              void* d_out, int out_size, void* d_ws, size_t ws_size,
                              hipStream_t stream) {
  P34 prm;
  for (int i = 0; i < 34; ++i) prm.p[i] = (const float*)d_in[i];
  prm.out = (float*)d_out;
  dim3 grid(BATCH/16), block(256);   // 16 chains per block (4 waves x 4 groups)
  hipLaunchKernelGGL(dvbf_fwd, grid, block, 0, stream, prm);
}